// Round 1
// baseline (307.427 us; speedup 1.0000x reference)
//
#include <hip/hip_runtime.h>

typedef unsigned short u16;
typedef __attribute__((ext_vector_type(8))) short short8;
typedef __attribute__((ext_vector_type(4))) float floatx4;

#define DEVI static __device__ __forceinline__

DEVI float bf2f(u16 u) {
  union { unsigned u; float f; } x; x.u = ((unsigned)u) << 16; return x.f;
}
DEVI u16 f2bf(float f) {
  union { float f; unsigned u; } x; x.f = f;
  unsigned r = x.u + 0x7fffu + ((x.u >> 16) & 1u);  // RNE
  return (u16)(r >> 16);
}

// async global->LDS, 16 B per lane, wave-uniform LDS base (dest = base + lane*16)
typedef __attribute__((address_space(1))) const void gas_t;
typedef __attribute__((address_space(3))) void las_t;
DEVI void glds16(const void* g, void* l) {
  __builtin_amdgcn_global_load_lds((gas_t*)g, (las_t*)l, 16, 0, 0);
}

#define BM 128
#define BN 128
#define BK 32

// ---- workspace layouts ----
// OLD 128-panels (dense GEMM / ctx / Wd_t): tile (rb,kb) 128x32 contiguous at
//   ((rb*(K/32))+kb)*4096 u16, elem (r,k) -> r*32 + (k&31).
// NEW 256-panels (QKV GEMM, swizzled): tile (rb,kt) 256x64 contiguous at
//   ((rb*(K/64))+kt)*16384 u16, elem (r,c) -> r*64 + (c ^ ((r&7)<<3)).
//   (swizzle baked into global data; global_load_lds stays linear; ds_read
//    applies the same XOR -> bank-conflict-free, rule "both-sides-or-neither")
// Q: row-major [head][t][128].
// K flash tiles: elem (h,t,d) ->
//   h*262144 + (t>>6)*8192 + (d>>5)*2048 + (t&63)*32 + (d&31)
// V flash tiles: elem (h,t,d) ->
//   h*262144 + (t>>6)*8192 + ((t&63)>>5)*4096 + d*32 + (t&31)

// ---------------- legacy 128x128 GEMM (dense epilogue + fallback) ----------
__global__ __launch_bounds__(256)
void gemm_kernel(const void* __restrict__ Av, const void* __restrict__ Bv,
                 int K, int lda, int ldb,
                 long sAz, long sBz, int mode, int head0, int aF32, int bF32,
                 const float* __restrict__ bias,
                 u16* __restrict__ out0, u16* __restrict__ out1,
                 u16* __restrict__ out2, float* __restrict__ outf)
{
  const int bn = blockIdx.x, bm = blockIdx.y, z = blockIdx.z;
  const int m0 = bm * BM, n0 = bn * BN;
  const int nkb = K >> 5;

  const float* Af = (const float*)Av;
  const u16*   Ab = (const u16*)Av + (long)z * sAz;
  const float* Bf = (const float*)Bv;
  const u16*   Bb = (const u16*)Bv + (long)z * sBz;

  __shared__ __align__(16) u16 As[BM * BK];   // [m][k] bf16
  __shared__ __align__(16) u16 Bs[BN * BK];   // [n][k] bf16

  const int tid  = threadIdx.x;
  const int lane = tid & 63;
  const int wave = tid >> 6;
  const int wm   = (wave & 1) * 64;
  const int wn   = (wave >> 1) * 64;
  const int lr   = lane & 15;
  const int quad = lane >> 4;

  floatx4 acc[4][4];
  #pragma unroll
  for (int i = 0; i < 4; i++)
    #pragma unroll
    for (int j = 0; j < 4; j++)
      acc[i][j] = floatx4{0.f, 0.f, 0.f, 0.f};

  for (int kb = 0; kb < nkb; kb++) {
    const int k0 = kb * BK;
    __syncthreads();
    if (aF32) {
      #pragma unroll
      for (int L = tid; L < 1024; L += 256) {
        int row = L >> 3, c4 = (L & 7) * 4;
        float4 v = *(const float4*)(Af + (long)(m0 + row) * lda + k0 + c4);
        ushort4 p;
        p.x = f2bf(v.x); p.y = f2bf(v.y); p.z = f2bf(v.z); p.w = f2bf(v.w);
        *(ushort4*)(&As[row * BK + c4]) = p;
      }
    } else {
      const u16* At = Ab + ((long)bm * nkb + kb) * 4096;
      #pragma unroll
      for (int it = 0; it < 2; it++) {
        int Cb = (wave * 2 + it) * 64;
        glds16(At + (long)(Cb + lane) * 8, &As[Cb * 8]);
      }
    }
    if (bF32) {
      #pragma unroll
      for (int L = tid; L < 1024; L += 256) {
        int kr = L >> 5, n4 = (L & 31) * 4;
        float4 v = *(const float4*)(Bf + (long)(k0 + kr) * ldb + n0 + n4);
        Bs[(n4 + 0) * BK + kr] = f2bf(v.x);
        Bs[(n4 + 1) * BK + kr] = f2bf(v.y);
        Bs[(n4 + 2) * BK + kr] = f2bf(v.z);
        Bs[(n4 + 3) * BK + kr] = f2bf(v.w);
      }
    } else {
      const u16* Bt = Bb + ((long)bn * nkb + kb) * 4096;
      #pragma unroll
      for (int it = 0; it < 2; it++) {
        int Cb = (wave * 2 + it) * 64;
        glds16(Bt + (long)(Cb + lane) * 8, &Bs[Cb * 8]);
      }
    }
    __syncthreads();

    short8 af[4], bf[4];
    #pragma unroll
    for (int i = 0; i < 4; i++)
      af[i] = *(const short8*)(&As[(wm + i * 16 + lr) * BK + quad * 8]);
    #pragma unroll
    for (int j = 0; j < 4; j++)
      bf[j] = *(const short8*)(&Bs[(wn + j * 16 + lr) * BK + quad * 8]);
    #pragma unroll
    for (int i = 0; i < 4; i++)
      #pragma unroll
      for (int j = 0; j < 4; j++)
        acc[i][j] = __builtin_amdgcn_mfma_f32_16x16x32_bf16(af[i], bf[j], acc[i][j], 0, 0, 0);
  }

  #pragma unroll
  for (int i = 0; i < 4; i++) {
    #pragma unroll
    for (int j = 0; j < 4; j++) {
      const int col = n0 + wn + j * 16 + lr;
      const int t0  = m0 + wm + i * 16 + quad * 4;   // row for r=0
      if (mode == 0) {
        int head = col / 384;
        int w = col - head * 384;
        long hbase = (long)head * 262144;
        float b = bias[col];
        if (w < 128) {          // Q row-major, pre-scaled by 1/sqrt(128)
          #pragma unroll
          for (int r = 0; r < 4; r++)
            out0[hbase + (long)(t0 + r) * 128 + w] =
                f2bf((acc[i][j][r] + b) * 0.08838834764831845f);
        } else if (w < 256) {   // K flash tiles (t-major inside chunk)
          int d = w - 128;
          long base = hbase + (long)(t0 >> 6) * 8192 + (d >> 5) * 2048 + (d & 31);
          #pragma unroll
          for (int r = 0; r < 4; r++)
            out1[base + ((t0 & 63) + r) * 32] = f2bf(acc[i][j][r] + b);
        } else {                // V flash tiles: r-contiguous -> ushort4
          int d = w - 256;
          long base = hbase + (long)(t0 >> 6) * 8192 + ((t0 & 63) >> 5) * 4096
                    + d * 32 + (t0 & 31);
          ushort4 p;
          p.x = f2bf(acc[i][j][0] + b);
          p.y = f2bf(acc[i][j][1] + b);
          p.z = f2bf(acc[i][j][2] + b);
          p.w = f2bf(acc[i][j][3] + b);
          *(ushort4*)(&out2[base]) = p;
        }
      } else {
        float b = bias[col];
        #pragma unroll
        for (int r = 0; r < 4; r++)
          outf[(long)(t0 + r) * 2048 + col] = acc[i][j][r] + b;
      }
    }
  }
}

// ---------------- 8-phase 256x256 QKV GEMM (T1+T2+T3+T4+T5) ----------------
// 512 thr = 8 waves (2M x 4N), per-wave 128x64 out, BK=64, LDS 128 KiB dbuf.
// Per K-tile T: 4 phases, one 64x32 C-quadrant (qm,qn) each, 16 MFMA/phase.
// Stage schedule (half-tile = 128 rows = 16 KB, 2 glds16/thread):
//   ph1: (T+1).A0 -> buf^1    ph2: (T+1).A1 -> buf^1
//   ph3: (T+2).B0 -> buf      ph4: (T+2).B1 -> buf
// Safety ledger: A-half last ds_read at ph3, B-half at ph2; each stage lands
// into a region past its last read by >=1 end-of-phase barrier.
// vmcnt(4) at ph4: outstanding = {T+1.B0,B1,A0,A1, T+2.B0,B1} (12 issues)
// -> drain to 4 covers tile T+1 exactly, leaves (T+2).B0/B1 in flight.
#define PH_SYNC() do { \
    __builtin_amdgcn_s_barrier(); \
    asm volatile("s_waitcnt lgkmcnt(0)" ::: "memory"); \
    __builtin_amdgcn_sched_barrier(0); \
  } while (0)

#define PH_MFMA(QM, QN) do { \
    __builtin_amdgcn_s_setprio(1); \
    _Pragma("unroll") \
    for (int i_ = 0; i_ < 4; ++i_) { \
      _Pragma("unroll") \
      for (int j_ = 0; j_ < 2; ++j_) { \
        acc[QM][QN][i_][j_] = __builtin_amdgcn_mfma_f32_16x16x32_bf16( \
            a[i_][0], b2[QN][j_][0], acc[QM][QN][i_][j_], 0, 0, 0); \
        acc[QM][QN][i_][j_] = __builtin_amdgcn_mfma_f32_16x16x32_bf16( \
            a[i_][1], b2[QN][j_][1], acc[QM][QN][i_][j_], 0, 0, 0); \
      } \
    } \
    __builtin_amdgcn_s_setprio(0); \
  } while (0)

__global__ __launch_bounds__(512, 2)
void gemm8_kernel(const u16* __restrict__ Ap, const u16* __restrict__ Bp,
                  int NKT, const float* __restrict__ bias,
                  u16* __restrict__ outQ, u16* __restrict__ outK,
                  u16* __restrict__ outV)
{
  // XCD swizzle: 192 WGs -> each XCD gets 24 contiguous wg = one bm row
  // (A row-panel = 1 MB stays L2-resident per XCD; B streams through L3)
  int lin = blockIdx.x + gridDim.x * blockIdx.y;
  int cpx = (gridDim.x * gridDim.y) >> 3;
  int wg  = (lin & 7) * cpx + (lin >> 3);
  const int bn = wg % gridDim.x;
  const int bm = wg / gridDim.x;
  const int m0 = bm << 8, n0 = bn << 8;

  __shared__ __align__(16) u16 As[2][16384];   // 64 KiB
  __shared__ __align__(16) u16 Bs[2][16384];   // 64 KiB

  const int tid  = threadIdx.x;
  const int lane = tid & 63, wave = tid >> 6;
  const int lr   = lane & 15, quad = lane >> 4;
  const int wm   = (wave >> 2) << 7;   // 0 / 128
  const int wn   = (wave & 3) << 6;    // 0 / 64 / 128 / 192
  const int ch0  = wave * 2;           // staging chunk pair
  const int axor = (lr & 7) << 3;      // XOR-swizzle (16B granular)
  const int cA   = (quad * 8) ^ axor;        // kk=0 swizzled col
  const int cB   = (32 + quad * 8) ^ axor;   // kk=1 swizzled col

  const u16* At = Ap + (long)bm * NKT * 16384;
  const u16* Bt = Bp + (long)bn * NKT * 16384;

#define STAGE_HALF(gsrc, ldst) do { \
    glds16((gsrc) + ch0 * 512 + lane * 8,       (ldst) + ch0 * 512); \
    glds16((gsrc) + ch0 * 512 + 512 + lane * 8, (ldst) + ch0 * 512 + 512); \
  } while (0)

  floatx4 acc[2][2][4][2];
  #pragma unroll
  for (int q = 0; q < 2; ++q)
    #pragma unroll
    for (int p = 0; p < 2; ++p)
      #pragma unroll
      for (int i = 0; i < 4; ++i)
        #pragma unroll
        for (int j = 0; j < 2; ++j)
          acc[q][p][i][j] = floatx4{0.f, 0.f, 0.f, 0.f};

  short8 a[4][2], b2[2][2][2];

  // prologue: tile0 fully + tile1.B0/B1; vmcnt(4) covers tile0 exactly
  STAGE_HALF(At,        &As[0][0]);
  STAGE_HALF(At + 8192, &As[0][8192]);
  STAGE_HALF(Bt,        &Bs[0][0]);
  STAGE_HALF(Bt + 8192, &Bs[0][8192]);
  if (NKT > 1) {
    STAGE_HALF(Bt + 16384,        &Bs[1][0]);
    STAGE_HALF(Bt + 16384 + 8192, &Bs[1][8192]);
    asm volatile("s_waitcnt vmcnt(4)" ::: "memory");
  } else {
    asm volatile("s_waitcnt vmcnt(0)" ::: "memory");
  }
  __builtin_amdgcn_s_barrier();

  for (int T = 0; T < NKT; ++T) {
    u16* Ac = &As[T & 1][0];
    u16* Bc = &Bs[T & 1][0];
    u16* An = &As[(T & 1) ^ 1][0];
    const u16* Ag = At + (long)(T + 1) * 16384;
    const u16* Bg = Bt + (long)(T + 2) * 16384;
    const bool s1 = (T + 1 < NKT), s2 = (T + 2 < NKT);

    // ---- phase 1: (qm0, qn0) -- 12 ds_read_b128
    #pragma unroll
    for (int i = 0; i < 4; ++i) {
      int rb = (wm + i * 16 + lr) * 64;
      a[i][0] = *(const short8*)&Ac[rb + cA];
      a[i][1] = *(const short8*)&Ac[rb + cB];
    }
    #pragma unroll
    for (int j = 0; j < 2; ++j) {
      int rb = (wn + j * 16 + lr) * 64;
      b2[0][j][0] = *(const short8*)&Bc[rb + cA];
      b2[0][j][1] = *(const short8*)&Bc[rb + cB];
    }
    if (s1) STAGE_HALF(Ag, An);
    PH_SYNC();
    PH_MFMA(0, 0);
    __builtin_amdgcn_s_barrier();

    // ---- phase 2: (qm0, qn1) -- 4 ds_read_b128
    #pragma unroll
    for (int j = 0; j < 2; ++j) {
      int rb = (wn + 32 + j * 16 + lr) * 64;
      b2[1][j][0] = *(const short8*)&Bc[rb + cA];
      b2[1][j][1] = *(const short8*)&Bc[rb + cB];
    }
    if (s1) STAGE_HALF(Ag + 8192, An + 8192);
    PH_SYNC();
    PH_MFMA(0, 1);
    __builtin_amdgcn_s_barrier();

    // ---- phase 3: (qm1, qn0) -- 8 ds_read_b128
    #pragma unroll
    for (int i = 0; i < 4; ++i) {
      int rb = (wm + 64 + i * 16 + lr) * 64;
      a[i][0] = *(const short8*)&Ac[rb + cA];
      a[i][1] = *(const short8*)&Ac[rb + cB];
    }
    if (s2) STAGE_HALF(Bg, Bc);        // (T+2)&1 == T&1: current B buffer
    PH_SYNC();
    PH_MFMA(1, 0);
    __builtin_amdgcn_s_barrier();

    // ---- phase 4: (qm1, qn1) -- 0 ds_read
    if (s2) STAGE_HALF(Bg + 8192, Bc + 8192);
    PH_SYNC();
    PH_MFMA(1, 1);
    if (s2) asm volatile("s_waitcnt vmcnt(4)" ::: "memory");
    else    asm volatile("s_waitcnt vmcnt(0)" ::: "memory");  // tail drain
    __builtin_amdgcn_s_barrier();
  }

  // epilogue: QKV scatter (+bias), C/D layout col=lr, row=quad*4+r
  #pragma unroll
  for (int qm = 0; qm < 2; ++qm) {
    #pragma unroll
    for (int qn = 0; qn < 2; ++qn) {
      #pragma unroll
      for (int i = 0; i < 4; ++i) {
        #pragma unroll
        for (int j = 0; j < 2; ++j) {
          const int col = n0 + wn + qn * 32 + j * 16 + lr;
          const int t0  = m0 + wm + qm * 64 + i * 16 + quad * 4;
          const floatx4 v = acc[qm][qn][i][j];
          int head = col / 384;
          int w = col - head * 384;
          long hbase = (long)head * 262144;
          float b = bias[col];
          if (w < 128) {          // Q row-major, pre-scaled by 1/sqrt(128)
            #pragma unroll
            for (int r = 0; r < 4; ++r)
              outQ[hbase + (long)(t0 + r) * 128 + w] =
                  f2bf((v[r] + b) * 0.08838834764831845f);
          } else if (w < 256) {   // K flash tiles
            int d = w - 128;
            long base = hbase + (long)(t0 >> 6) * 8192 + (d >> 5) * 2048 + (d & 31);
            #pragma unroll
            for (int r = 0; r < 4; ++r)
              outK[base + ((t0 & 63) + r) * 32] = f2bf(v[r] + b);
          } else {                // V flash tiles
            int d = w - 256;
            long base = hbase + (long)(t0 >> 6) * 8192 + ((t0 & 63) >> 5) * 4096
                      + d * 32 + (t0 & 31);
            ushort4 p;
            p.x = f2bf(v[0] + b); p.y = f2bf(v[1] + b);
            p.z = f2bf(v[2] + b); p.w = f2bf(v[3] + b);
            *(ushort4*)(&outV[base]) = p;
          }
        }
      }
    }
  }
#undef STAGE_HALF
}

// ---------------- fused flash attention, v5 (XCD-pinned, static-shift) ----
__global__ __launch_bounds__(256, 2)
void flash_kernel(const u16* __restrict__ Qg, const u16* __restrict__ Kg,
                  const u16* __restrict__ Vg, u16* __restrict__ ctx)
{
  const int head = blockIdx.x, slot = blockIdx.y;
  const int qb   = (slot < 16) ? slot : 47 - slot;
  const int nkt  = qb + 1;               // 64-row K/V tiles
  const long HS  = 2048L * 128;
  const u16* Qh = Qg + (long)head * HS;
  const u16* Kh = Kg + (long)head * HS;  // flash-tile layout
  const u16* Vh = Vg + (long)head * HS;  // flash-tile layout

  __shared__ __align__(16) u16 k_s[2][8192];   // 2 x 16 KB  [kt][n][32]
  __shared__ __align__(16) u16 v_s[2][8192];   // 2 x 16 KB  [kt2][d][32]
  __shared__ __align__(16) u16 p_s[4 * 1088];  // 8.5 KB, per-wave 16 x stride-68

  const int tid  = threadIdx.x;
  const int lane = tid & 63, wv = tid >> 6;
  const int lr   = lane & 15, quad = lane >> 4;
  const int qs   = qb * 64 + wv * 16;
  const int pbase = wv * 1088;

  short8 qf[4];
  #pragma unroll
  for (int kt = 0; kt < 4; kt++)
    qf[kt] = *(const short8*)(Qh + (long)(qs + lr) * 128 + kt * 32 + quad * 8);

  float l_r[4];
  #pragma unroll
  for (int r = 0; r < 4; r++) l_r[r] = 0.f;

  floatx4 o[8];
  #pragma unroll
  for (int j = 0; j < 8; j++) o[j] = floatx4{0.f, 0.f, 0.f, 0.f};

  #pragma unroll
  for (int it = 0; it < 4; it++) {
    int Cb = (wv * 4 + it) * 64;
    glds16(Kh + (long)(Cb + lane) * 8, &k_s[0][Cb * 8]);
    glds16(Vh + (long)(Cb + lane) * 8, &v_s[0][Cb * 8]);
  }

  for (int kb = 0; kb < nkt; kb++) {
    const int cur = kb & 1;
    __syncthreads();                     // drains own DMA -> buf[cur] ready
    if (kb + 1 < nkt) {                  // prefetch tile kb+1 into buf[cur^1]
      const u16* Kt = Kh + (long)(kb + 1) * 8192;
      const u16* Vt = Vh + (long)(kb + 1) * 8192;
      #pragma unroll
      for (int it = 0; it < 4; it++) {
        int Cb = (wv * 4 + it) * 64;
        glds16(Kt + (long)(Cb + lane) * 8, &k_s[cur ^ 1][Cb * 8]);
        glds16(Vt + (long)(Cb + lane) * 8, &v_s[cur ^ 1][Cb * 8]);
      }
    }

    floatx4 sa[4];
    #pragma unroll
    for (int j = 0; j < 4; j++) sa[j] = floatx4{0.f, 0.f, 0.f, 0.f};
    #pragma unroll
    for (int kt = 0; kt < 4; kt++) {
      #pragma unroll
      for (int j = 0; j < 4; j++) {
        short8 bf = *(const short8*)(&k_s[cur][kt * 2048 + (j * 16 + lr) * 32 + quad * 8]);
        sa[j] = __builtin_amdgcn_mfma_f32_16x16x32_bf16(qf[kt], bf, sa[j], 0, 0, 0);
      }
    }

    if (kb == nkt - 1) {                 // causal mask, last tile only
      #pragma unroll
      for (int j = 0; j < 4; j++)
        #pragma unroll
        for (int r = 0; r < 4; r++) {
          int cg = kb * 64 + j * 16 + lr;
          int rg = qs + quad * 4 + r;
          if (cg > rg) sa[j][r] = -1e30f;
        }
    }

    #pragma unroll
    for (int r = 0; r < 4; r++) {
      float s0 = 0.f;
      #pragma unroll
      for (int j = 0; j < 4; j++) {
        float e = __expf(sa[j][r] - 8.f);
        p_s[pbase + (quad * 4 + r) * 68 + j * 16 + lr] = f2bf(e);
        s0 += e;
      }
      s0 += __shfl_xor(s0, 1, 16);
      s0 += __shfl_xor(s0, 2, 16);
      s0 += __shfl_xor(s0, 4, 16);
      s0 += __shfl_xor(s0, 8, 16);
      l_r[r] += s0;
    }

    #pragma unroll
    for (int kt2 = 0; kt2 < 2; kt2++) {
      short8 pa = *(const short8*)(&p_s[pbase + lr * 68 + kt2 * 32 + quad * 8]);
      #pragma unroll
      for (int j = 0; j < 8; j++) {
        short8 vb = *(const short8*)(&v_s[cur][kt2 * 4096 + (j * 16 + lr) * 32 + quad * 8]);
        o[j] = __builtin_amdgcn_mfma_f32_16x16x32_bf16(pa, vb, o[j], 0, 0, 0);
      }
    }
  } // kb

  #pragma unroll
  for (int r = 0; r < 4; r++) {
    float inv = 1.f / l_r[r];
    int row = qs + quad * 4 + r;
    long prow = ((long)(row >> 7) * 64) * 4096 + (row & 127) * 32;
    #pragma unroll
    for (int j = 0; j < 8; j++) {
      int c = head * 128 + j * 16 + lr;
      ctx[prow + (long)(c >> 5) * 4096 + (c & 31)] = f2bf(o[j][r] * inv);
    }
  }
}

// fp32 [M][K] row-major -> bf16 swizzled 256-PANELS. float4/thread.
__global__ __launch_bounds__(256)
void convert256_kernel(const float* __restrict__ in, u16* __restrict__ out,
                       int K, long n4)
{
  long i = (long)blockIdx.x * 256 + threadIdx.x;
  if (i < n4) {
    float4 v = ((const float4*)in)[i];
    ushort4 p;
    p.x = f2bf(v.x); p.y = f2bf(v.y); p.z = f2bf(v.z); p.w = f2bf(v.w);
    long e = i * 4;
    int row = (int)(e / K), k = (int)(e % K);
    int nkt = K >> 6;
    long d = ((long)(row >> 8) * nkt + (k >> 6)) * 16384
           + (row & 255) * 64 + ((k & 63) ^ ((row & 7) << 3));
    *(ushort4*)(&out[d]) = p;   // XOR flips bits>=3; 4-run stays contiguous
  }
}

// fp32 [K][N] -> bf16 swizzled 256-PANELS of the [N][K] transpose.
__global__ __launch_bounds__(256)
void transpose256_kernel(const float* __restrict__ in, u16* __restrict__ out,
                         int K, int N)
{
  __shared__ float t[32][33];
  int n0 = blockIdx.x * 32, k0 = blockIdx.y * 32;
  int tx = threadIdx.x & 31, ty = threadIdx.x >> 5;
  #pragma unroll
  for (int i = 0; i < 4; i++)
    t[ty + i * 8][tx] = in[(long)(k0 + ty + i * 8) * N + n0 + tx];
  __syncthreads();
  const int nkt = K >> 6;
  #pragma unroll
  for (int i = 0; i < 4; i++) {
    int n = n0 + ty + i * 8;
    int k = k0 + tx;
    long d = ((long)(n >> 8) * nkt + (k >> 6)) * 16384
           + (n & 255) * 64 + ((k & 63) ^ ((n & 7) << 3));
    out[d] = f2bf(t[tx][ty + i * 8]);
  }
}

// fp32 [K][N] -> bf16 legacy 128-PANELS of the [N][K] transpose. 32x32 tiles.
__global__ __launch_bounds__(256)
void transpose_bf16_kernel(const float* __restrict__ in, u16* __restrict__ out,
                           int K, int N)
{
  __shared__ float t[32][33];
  int n0 = blockIdx.x * 32, k0 = blockIdx.y * 32;
  int tx = threadIdx.x & 31, ty = threadIdx.x >> 5;
  #pragma unroll
  for (int i = 0; i < 4; i++)
    t[ty + i * 8][tx] = in[(long)(k0 + ty + i * 8) * N + n0 + tx];
  __syncthreads();
  const int nkb = K >> 5;
  #pragma unroll
  for (int i = 0; i < 4; i++) {
    int n = n0 + ty + i * 8;
    int k = k0 + tx;
    long d = ((long)(n >> 7) * nkb + (k >> 5)) * 4096 + (n & 127) * 32 + (k & 31);
    out[d] = f2bf(t[tx][ty + i * 8]);
  }
}

// RoPE in-place on first 32 dims of Q (row-major) and K (flash tiles).
__global__ __launch_bounds__(256)
void rope_kernel(u16* __restrict__ Q, u16* __restrict__ K)
{
  int idx = blockIdx.x * 256 + threadIdx.x;
  int i = idx & 15;
  int s = (idx >> 4) & 2047;
  int head = (idx >> 15) & 15;
  int isK = (idx >> 19);
  float inv_freq = exp2f(-(float)i * 0.83048202372184058696f); // 10000^(-i/16)
  float ang = (float)s * inv_freq;
  float c = cosf(ang), sn = sinf(ang);
  long b0, b1;
  u16* buf;
  if (isK) {
    buf = K;
    long base = (long)head * 262144 + (long)(s >> 6) * 8192 + (s & 63) * 32;
    b0 = base + i;
    b1 = base + i + 16;
  } else {
    buf = Q;
    long base = ((long)head * 2048 + s) * 128;
    b0 = base + i;
    b1 = base + i + 16;
  }
  float x1 = bf2f(buf[b0]);
  float x2 = bf2f(buf[b1]);
  buf[b0] = f2bf(x1 * c - x2 * sn);
  buf[b1] = f2bf(x2 * c + x1 * sn);
}

extern "C" void kernel_launch(void* const* d_in, const int* in_sizes, int n_in,
                              void* d_out, int out_size, void* d_ws, size_t ws_size,
                              hipStream_t stream)
{
  const float* hidden = (const float*)d_in[0];   // [2048][2048] f32
  const float* Wqkv   = (const float*)d_in[1];   // [2048][6144] f32
  const float* bqkv   = (const float*)d_in[2];   // [6144] f32
  const float* Wd     = (const float*)d_in[3];   // [2048][2048] f32
  const float* bd     = (const float*)d_in[4];   // [2048] f32
  float* out = (float*)d_out;                    // [2048][2048] f32

  char* ws = (char*)d_ws;
  u16* Q   = (u16*)(ws);                      //  8 MB  Q row-major
  u16* Kb  = (u16*)(ws + (8ull  << 20));      //  8 MB  K flash tiles
  u16* Vt  = (u16*)(ws + (16ull << 20));      //  8 MB  V flash tiles
  u16* ctx = (u16*)(ws + (24ull << 20));      //  8 MB  ctx panels (128-layout)
  char* regA = ws + (32ull << 20);            // overlay region

  const bool fast = ws_size >= (64ull << 20);

  if (fast) {
    u16* hidden_bf = (u16*)(regA);                  // 8 MB 256-panels, then Wd_t
    u16* Wqkv_t    = (u16*)(regA + (8ull << 20));   // 24 MB 256-panels
    u16* Wd_t      = (u16*)(regA);                  // 8 MB 128-panels

    convert256_kernel<<<dim3(4096), 256, 0, stream>>>(hidden, hidden_bf, 2048, 1048576);
    transpose256_kernel<<<dim3(192, 64), 256, 0, stream>>>(Wqkv, Wqkv_t, 2048, 6144);

    gemm8_kernel<<<dim3(24, 8), 512, 0, stream>>>(
        hidden_bf, Wqkv_t, /*NKT*/32, bqkv, Q, Kb, Vt);

    rope_kernel<<<dim3(4096), 256, 0, stream>>>(Q, Kb);
    transpose_bf16_kernel<<<dim3(64, 64), 256, 0, stream>>>(Wd, Wd_t, 2048, 2048);

    flash_kernel<<<dim3(16, 32), 256, 0, stream>>>(Q, Kb, Vt, ctx);

    gemm_kernel<<<dim3(16, 16, 1), 256, 0, stream>>>(
        ctx, Wd_t, 2048, 2048, 2048, 0, 0, /*mode*/3, 0, 0, 0, bd,
        nullptr, nullptr, nullptr, out);
  } else {
    gemm_kernel<<<dim3(48, 16, 1), 256, 0, stream>>>(
        hidden, Wqkv, 2048, 2048, 6144, 0, 0, /*mode*/0, 0, 1, 1, bqkv,
        Q, Kb, Vt, nullptr);
    rope_kernel<<<dim3(4096), 256, 0, stream>>>(Q, Kb);
    flash_kernel<<<dim3(16, 32), 256, 0, stream>>>(Q, Kb, Vt, ctx);
    gemm_kernel<<<dim3(16, 16, 1), 256, 0, stream>>>(
        ctx, Wd, 2048, 2048, 2048, 0, 0, /*mode*/3, 0, 0, 1, bd,
        nullptr, nullptr, nullptr, out);
  }
}

// Round 2
// 306.737 us; speedup vs baseline: 1.0022x; 1.0022x over previous
//
#include <hip/hip_runtime.h>

typedef unsigned short u16;
typedef __attribute__((ext_vector_type(8))) short short8;
typedef __attribute__((ext_vector_type(4))) float floatx4;

#define DEVI static __device__ __forceinline__

DEVI float bf2f(u16 u) {
  union { unsigned u; float f; } x; x.u = ((unsigned)u) << 16; return x.f;
}
DEVI u16 f2bf(float f) {
  union { float f; unsigned u; } x; x.f = f;
  unsigned r = x.u + 0x7fffu + ((x.u >> 16) & 1u);  // RNE
  return (u16)(r >> 16);
}

// async global->LDS, 16 B per lane, wave-uniform LDS base (dest = base + lane*16)
typedef __attribute__((address_space(1))) const void gas_t;
typedef __attribute__((address_space(3))) void las_t;
DEVI void glds16(const void* g, void* l) {
  __builtin_amdgcn_global_load_lds((gas_t*)g, (las_t*)l, 16, 0, 0);
}

#define BM 128
#define BN 128
#define BK 32

// ---- workspace layouts ----
// 128-panels (dense GEMM / ctx / Wd_t): tile (rb,kb) 128x32 contiguous at
//   ((rb*(K/32))+kb)*4096 u16, elem (r,k) -> r*32 + (k&31).
// 256-panels (QKV GEMM, swizzled): tile (rb,kt) 256x64 contiguous at
//   ((rb*(K/64))+kt)*16384 u16, elem (r,c) -> r*64 + (c ^ ((r&7)<<3)).
// Q: row-major [head][t][128].
// K flash tiles: elem (h,t,d) ->
//   h*262144 + (t>>6)*8192 + (d>>5)*2048 + (t&63)*32 + (d&31)
// V flash tiles: elem (h,t,d) ->
//   h*262144 + (t>>6)*8192 + ((t&63)>>5)*4096 + d*32 + (t&31)

// ---------------- legacy 128x128 GEMM (fallback paths) ---------------------
__global__ __launch_bounds__(256)
void gemm_kernel(const void* __restrict__ Av, const void* __restrict__ Bv,
                 int K, int lda, int ldb,
                 long sAz, long sBz, int mode, int head0, int aF32, int bF32,
                 const float* __restrict__ bias,
                 u16* __restrict__ out0, u16* __restrict__ out1,
                 u16* __restrict__ out2, float* __restrict__ outf)
{
  const int bn = blockIdx.x, bm = blockIdx.y, z = blockIdx.z;
  const int m0 = bm * BM, n0 = bn * BN;
  const int nkb = K >> 5;

  const float* Af = (const float*)Av;
  const u16*   Ab = (const u16*)Av + (long)z * sAz;
  const float* Bf = (const float*)Bv;
  const u16*   Bb = (const u16*)Bv + (long)z * sBz;

  __shared__ __align__(16) u16 As[BM * BK];   // [m][k] bf16
  __shared__ __align__(16) u16 Bs[BN * BK];   // [n][k] bf16

  const int tid  = threadIdx.x;
  const int lane = tid & 63;
  const int wave = tid >> 6;
  const int wm   = (wave & 1) * 64;
  const int wn   = (wave >> 1) * 64;
  const int lr   = lane & 15;
  const int quad = lane >> 4;

  floatx4 acc[4][4];
  #pragma unroll
  for (int i = 0; i < 4; i++)
    #pragma unroll
    for (int j = 0; j < 4; j++)
      acc[i][j] = floatx4{0.f, 0.f, 0.f, 0.f};

  for (int kb = 0; kb < nkb; kb++) {
    const int k0 = kb * BK;
    __syncthreads();
    if (aF32) {
      #pragma unroll
      for (int L = tid; L < 1024; L += 256) {
        int row = L >> 3, c4 = (L & 7) * 4;
        float4 v = *(const float4*)(Af + (long)(m0 + row) * lda + k0 + c4);
        ushort4 p;
        p.x = f2bf(v.x); p.y = f2bf(v.y); p.z = f2bf(v.z); p.w = f2bf(v.w);
        *(ushort4*)(&As[row * BK + c4]) = p;
      }
    } else {
      const u16* At = Ab + ((long)bm * nkb + kb) * 4096;
      #pragma unroll
      for (int it = 0; it < 2; it++) {
        int Cb = (wave * 2 + it) * 64;
        glds16(At + (long)(Cb + lane) * 8, &As[Cb * 8]);
      }
    }
    if (bF32) {
      #pragma unroll
      for (int L = tid; L < 1024; L += 256) {
        int kr = L >> 5, n4 = (L & 31) * 4;
        float4 v = *(const float4*)(Bf + (long)(k0 + kr) * ldb + n0 + n4);
        Bs[(n4 + 0) * BK + kr] = f2bf(v.x);
        Bs[(n4 + 1) * BK + kr] = f2bf(v.y);
        Bs[(n4 + 2) * BK + kr] = f2bf(v.z);
        Bs[(n4 + 3) * BK + kr] = f2bf(v.w);
      }
    } else {
      const u16* Bt = Bb + ((long)bn * nkb + kb) * 4096;
      #pragma unroll
      for (int it = 0; it < 2; it++) {
        int Cb = (wave * 2 + it) * 64;
        glds16(Bt + (long)(Cb + lane) * 8, &Bs[Cb * 8]);
      }
    }
    __syncthreads();

    short8 af[4], bf[4];
    #pragma unroll
    for (int i = 0; i < 4; i++)
      af[i] = *(const short8*)(&As[(wm + i * 16 + lr) * BK + quad * 8]);
    #pragma unroll
    for (int j = 0; j < 4; j++)
      bf[j] = *(const short8*)(&Bs[(wn + j * 16 + lr) * BK + quad * 8]);
    #pragma unroll
    for (int i = 0; i < 4; i++)
      #pragma unroll
      for (int j = 0; j < 4; j++)
        acc[i][j] = __builtin_amdgcn_mfma_f32_16x16x32_bf16(af[i], bf[j], acc[i][j], 0, 0, 0);
  }

  #pragma unroll
  for (int i = 0; i < 4; i++) {
    #pragma unroll
    for (int j = 0; j < 4; j++) {
      const int col = n0 + wn + j * 16 + lr;
      const int t0  = m0 + wm + i * 16 + quad * 4;   // row for r=0
      if (mode == 0) {
        int head = col / 384;
        int w = col - head * 384;
        long hbase = (long)head * 262144;
        float b = bias[col];
        if (w < 128) {          // Q row-major, pre-scaled by 1/sqrt(128)
          #pragma unroll
          for (int r = 0; r < 4; r++)
            out0[hbase + (long)(t0 + r) * 128 + w] =
                f2bf((acc[i][j][r] + b) * 0.08838834764831845f);
        } else if (w < 256) {   // K flash tiles (t-major inside chunk)
          int d = w - 128;
          long base = hbase + (long)(t0 >> 6) * 8192 + (d >> 5) * 2048 + (d & 31);
          #pragma unroll
          for (int r = 0; r < 4; r++)
            out1[base + ((t0 & 63) + r) * 32] = f2bf(acc[i][j][r] + b);
        } else {                // V flash tiles: r-contiguous -> ushort4
          int d = w - 256;
          long base = hbase + (long)(t0 >> 6) * 8192 + ((t0 & 63) >> 5) * 4096
                    + d * 32 + (t0 & 31);
          ushort4 p;
          p.x = f2bf(acc[i][j][0] + b);
          p.y = f2bf(acc[i][j][1] + b);
          p.z = f2bf(acc[i][j][2] + b);
          p.w = f2bf(acc[i][j][3] + b);
          *(ushort4*)(&out2[base]) = p;
        }
      } else {
        float b = bias[col];
        #pragma unroll
        for (int r = 0; r < 4; r++)
          outf[(long)(t0 + r) * 2048 + col] = acc[i][j][r] + b;
      }
    }
  }
}

// ---------------- dense 128x64 GEMM, 2 WG/CU (ctx @ Wd_t -> out f32) -------
// m97 structure at 1 WG/CU (grid 16x16) sat at ~320 TF (m102 N=2048 point);
// halving BN doubles the grid to 512 WGs = 2 WG/CU for barrier-drain TLP.
// A = ctx 128-panels; B = Wd_t 128-panels (64-row sub-panel is contiguous).
__global__ __launch_bounds__(256)
void gemm_dense_kernel(const u16* __restrict__ Ap, const u16* __restrict__ Bp,
                       int nkb, const float* __restrict__ bias,
                       float* __restrict__ outf)
{
  const int bn = blockIdx.x, bm = blockIdx.y;
  const int m0 = bm << 7, n0 = bn << 6;

  __shared__ __align__(16) u16 As[128 * 32];   // 8 KB
  __shared__ __align__(16) u16 Bs[64 * 32];    // 4 KB

  const int tid  = threadIdx.x;
  const int lane = tid & 63;
  const int wave = tid >> 6;
  const int wm   = (wave & 1) * 64;
  const int wn   = (wave >> 1) * 32;
  const int lr   = lane & 15;
  const int quad = lane >> 4;

  floatx4 acc[4][2];
  #pragma unroll
  for (int i = 0; i < 4; i++)
    #pragma unroll
    for (int j = 0; j < 2; j++)
      acc[i][j] = floatx4{0.f, 0.f, 0.f, 0.f};

  // B sub-panel base: cols n0..n0+63 of 128-panel (n0>>7), offset (n0&127)*32
  const u16* Bbase = Bp + (long)(n0 >> 7) * nkb * 4096 + (long)(n0 & 127) * 32;

  for (int kb = 0; kb < nkb; kb++) {
    __syncthreads();
    const u16* At = Ap + ((long)bm * nkb + kb) * 4096;
    const u16* Bt = Bbase + (long)kb * 4096;
    #pragma unroll
    for (int it = 0; it < 2; it++) {
      int c = wave * 2 + it;
      glds16(At + c * 512 + lane * 8, &As[c * 512]);
    }
    glds16(Bt + wave * 512 + lane * 8, &Bs[wave * 512]);
    __syncthreads();

    short8 af[4], bf[2];
    #pragma unroll
    for (int i = 0; i < 4; i++)
      af[i] = *(const short8*)(&As[(wm + i * 16 + lr) * 32 + quad * 8]);
    #pragma unroll
    for (int j = 0; j < 2; j++)
      bf[j] = *(const short8*)(&Bs[(wn + j * 16 + lr) * 32 + quad * 8]);
    #pragma unroll
    for (int i = 0; i < 4; i++)
      #pragma unroll
      for (int j = 0; j < 2; j++)
        acc[i][j] = __builtin_amdgcn_mfma_f32_16x16x32_bf16(af[i], bf[j], acc[i][j], 0, 0, 0);
  }

  #pragma unroll
  for (int i = 0; i < 4; i++) {
    #pragma unroll
    for (int j = 0; j < 2; j++) {
      const int col = n0 + wn + j * 16 + lr;
      const int t0  = m0 + wm + i * 16 + quad * 4;
      float b = bias[col];
      #pragma unroll
      for (int r = 0; r < 4; r++)
        outf[(long)(t0 + r) * 2048 + col] = acc[i][j][r] + b;
    }
  }
}

// ---------------- 8-phase 256x256 QKV GEMM (T1+T2+T3+T4+T5) ----------------
// 512 thr = 8 waves (2M x 4N), per-wave 128x64 out, BK=64, LDS 128 KiB dbuf.
// Per K-tile T: 4 phases, one 64x32 C-quadrant (qm,qn) each, 16 MFMA/phase.
// DEEP-PREFETCH schedule (v2): ALL of tile T+2 staged during tile T:
//   ph3: (T+2).B0+B1 -> Bs[T&1]   (B-half reads complete by end-ph2 barrier)
//   ph4: (T+2).A0+A1 -> As[T&1]   (A-half reads complete by end-ph3 barrier)
// Steady state outstanding at end-ph4 = 16 glds16 (T+1's 8 + T+2's 8);
// vmcnt(8) drains exactly tile T+1, issued 4-6 phases (~2500 cy) earlier
// -> HBM/L2 latency fully covered (v1 waited on loads only 2 phases old).
#define PH_SYNC() do { \
    __builtin_amdgcn_s_barrier(); \
    asm volatile("s_waitcnt lgkmcnt(0)" ::: "memory"); \
    __builtin_amdgcn_sched_barrier(0); \
  } while (0)

#define PH_MFMA(QM, QN) do { \
    __builtin_amdgcn_s_setprio(1); \
    _Pragma("unroll") \
    for (int i_ = 0; i_ < 4; ++i_) { \
      _Pragma("unroll") \
      for (int j_ = 0; j_ < 2; ++j_) { \
        acc[QM][QN][i_][j_] = __builtin_amdgcn_mfma_f32_16x16x32_bf16( \
            a[i_][0], b2[QN][j_][0], acc[QM][QN][i_][j_], 0, 0, 0); \
        acc[QM][QN][i_][j_] = __builtin_amdgcn_mfma_f32_16x16x32_bf16( \
            a[i_][1], b2[QN][j_][1], acc[QM][QN][i_][j_], 0, 0, 0); \
      } \
    } \
    __builtin_amdgcn_s_setprio(0); \
  } while (0)

__global__ __launch_bounds__(512, 2)
void gemm8_kernel(const u16* __restrict__ Ap, const u16* __restrict__ Bp,
                  int NKT, const float* __restrict__ bias,
                  u16* __restrict__ outQ, u16* __restrict__ outK,
                  u16* __restrict__ outV)
{
  // XCD swizzle: 192 WGs -> each XCD gets 24 contiguous wg = one bm row
  int lin = blockIdx.x + gridDim.x * blockIdx.y;
  int cpx = (gridDim.x * gridDim.y) >> 3;
  int wg  = (lin & 7) * cpx + (lin >> 3);
  const int bn = wg % gridDim.x;
  const int bm = wg / gridDim.x;
  const int m0 = bm << 8, n0 = bn << 8;

  __shared__ __align__(16) u16 As[2][16384];   // 64 KiB
  __shared__ __align__(16) u16 Bs[2][16384];   // 64 KiB

  const int tid  = threadIdx.x;
  const int lane = tid & 63, wave = tid >> 6;
  const int lr   = lane & 15, quad = lane >> 4;
  const int wm   = (wave >> 2) << 7;   // 0 / 128
  const int wn   = (wave & 3) << 6;    // 0 / 64 / 128 / 192
  const int ch0  = wave * 2;           // staging chunk pair
  const int axor = (lr & 7) << 3;      // XOR-swizzle (16B granular)
  const int cA   = (quad * 8) ^ axor;        // kk=0 swizzled col
  const int cB   = (32 + quad * 8) ^ axor;   // kk=1 swizzled col

  const u16* At = Ap + (long)bm * NKT * 16384;
  const u16* Bt = Bp + (long)bn * NKT * 16384;

#define STAGE_HALF(gsrc, ldst) do { \
    glds16((gsrc) + ch0 * 512 + lane * 8,       (ldst) + ch0 * 512); \
    glds16((gsrc) + ch0 * 512 + 512 + lane * 8, (ldst) + ch0 * 512 + 512); \
  } while (0)

  floatx4 acc[2][2][4][2];
  #pragma unroll
  for (int q = 0; q < 2; ++q)
    #pragma unroll
    for (int p = 0; p < 2; ++p)
      #pragma unroll
      for (int i = 0; i < 4; ++i)
        #pragma unroll
        for (int j = 0; j < 2; ++j)
          acc[q][p][i][j] = floatx4{0.f, 0.f, 0.f, 0.f};

  short8 a[4][2], b2[2][2][2];

  // prologue: tiles 0 and 1 fully staged; vmcnt(8) -> tile0 landed
  STAGE_HALF(At,        &As[0][0]);
  STAGE_HALF(At + 8192, &As[0][8192]);
  STAGE_HALF(Bt,        &Bs[0][0]);
  STAGE_HALF(Bt + 8192, &Bs[0][8192]);
  if (NKT > 1) {
    STAGE_HALF(At + 16384,        &As[1][0]);
    STAGE_HALF(At + 16384 + 8192, &As[1][8192]);
    STAGE_HALF(Bt + 16384,        &Bs[1][0]);
    STAGE_HALF(Bt + 16384 + 8192, &Bs[1][8192]);
    asm volatile("s_waitcnt vmcnt(8)" ::: "memory");
  } else {
    asm volatile("s_waitcnt vmcnt(0)" ::: "memory");
  }
  __builtin_amdgcn_s_barrier();

  for (int T = 0; T < NKT; ++T) {
    u16* Ac = &As[T & 1][0];
    u16* Bc = &Bs[T & 1][0];
    const u16* Ag2 = At + (long)(T + 2) * 16384;
    const u16* Bg2 = Bt + (long)(T + 2) * 16384;
    const bool s2 = (T + 2 < NKT);

    // ---- phase 1: (qm0, qn0) -- 12 ds_read_b128
    #pragma unroll
    for (int i = 0; i < 4; ++i) {
      int rb = (wm + i * 16 + lr) * 64;
      a[i][0] = *(const short8*)&Ac[rb + cA];
      a[i][1] = *(const short8*)&Ac[rb + cB];
    }
    #pragma unroll
    for (int j = 0; j < 2; ++j) {
      int rb = (wn + j * 16 + lr) * 64;
      b2[0][j][0] = *(const short8*)&Bc[rb + cA];
      b2[0][j][1] = *(const short8*)&Bc[rb + cB];
    }
    PH_SYNC();
    PH_MFMA(0, 0);
    __builtin_amdgcn_s_barrier();

    // ---- phase 2: (qm0, qn1) -- 4 ds_read_b128 (last B reads of tile T)
    #pragma unroll
    for (int j = 0; j < 2; ++j) {
      int rb = (wn + 32 + j * 16 + lr) * 64;
      b2[1][j][0] = *(const short8*)&Bc[rb + cA];
      b2[1][j][1] = *(const short8*)&Bc[rb + cB];
    }
    PH_SYNC();
    PH_MFMA(0, 1);
    __builtin_amdgcn_s_barrier();

    // ---- phase 3: (qm1, qn0) -- 8 ds_read + stage (T+2).B0,B1 into Bc
    #pragma unroll
    for (int i = 0; i < 4; ++i) {
      int rb = (wm + 64 + i * 16 + lr) * 64;
      a[i][0] = *(const short8*)&Ac[rb + cA];
      a[i][1] = *(const short8*)&Ac[rb + cB];
    }
    if (s2) {
      STAGE_HALF(Bg2,        Bc);
      STAGE_HALF(Bg2 + 8192, Bc + 8192);
    }
    PH_SYNC();
    PH_MFMA(1, 0);
    __builtin_amdgcn_s_barrier();

    // ---- phase 4: (qm1, qn1) -- stage (T+2).A0,A1 into Ac
    if (s2) {
      STAGE_HALF(Ag2,        Ac);
      STAGE_HALF(Ag2 + 8192, Ac + 8192);
    }
    PH_SYNC();
    PH_MFMA(1, 1);
    if (s2) asm volatile("s_waitcnt vmcnt(8)" ::: "memory");
    else    asm volatile("s_waitcnt vmcnt(0)" ::: "memory");  // tail drain
    __builtin_amdgcn_s_barrier();
  }

  // epilogue: QKV scatter (+bias), C/D layout col=lr, row=quad*4+r
  #pragma unroll
  for (int qm = 0; qm < 2; ++qm) {
    #pragma unroll
    for (int qn = 0; qn < 2; ++qn) {
      #pragma unroll
      for (int i = 0; i < 4; ++i) {
        #pragma unroll
        for (int j = 0; j < 2; ++j) {
          const int col = n0 + wn + qn * 32 + j * 16 + lr;
          const int t0  = m0 + wm + qm * 64 + i * 16 + quad * 4;
          const floatx4 v = acc[qm][qn][i][j];
          int head = col / 384;
          int w = col - head * 384;
          long hbase = (long)head * 262144;
          float b = bias[col];
          if (w < 128) {          // Q row-major, pre-scaled by 1/sqrt(128)
            #pragma unroll
            for (int r = 0; r < 4; ++r)
              outQ[hbase + (long)(t0 + r) * 128 + w] =
                  f2bf((v[r] + b) * 0.08838834764831845f);
          } else if (w < 256) {   // K flash tiles
            int d = w - 128;
            long base = hbase + (long)(t0 >> 6) * 8192 + (d >> 5) * 2048 + (d & 31);
            #pragma unroll
            for (int r = 0; r < 4; ++r)
              outK[base + ((t0 & 63) + r) * 32] = f2bf(v[r] + b);
          } else {                // V flash tiles
            int d = w - 256;
            long base = hbase + (long)(t0 >> 6) * 8192 + ((t0 & 63) >> 5) * 4096
                      + d * 32 + (t0 & 31);
            ushort4 p;
            p.x = f2bf(v[0] + b); p.y = f2bf(v[1] + b);
            p.z = f2bf(v[2] + b); p.w = f2bf(v[3] + b);
            *(ushort4*)(&outV[base]) = p;
          }
        }
      }
    }
  }
#undef STAGE_HALF
}

// ---------------- fused flash attention, v5 (XCD-pinned, static-shift) ----
__global__ __launch_bounds__(256, 2)
void flash_kernel(const u16* __restrict__ Qg, const u16* __restrict__ Kg,
                  const u16* __restrict__ Vg, u16* __restrict__ ctx)
{
  const int head = blockIdx.x, slot = blockIdx.y;
  const int qb   = (slot < 16) ? slot : 47 - slot;
  const int nkt  = qb + 1;               // 64-row K/V tiles
  const long HS  = 2048L * 128;
  const u16* Qh = Qg + (long)head * HS;
  const u16* Kh = Kg + (long)head * HS;  // flash-tile layout
  const u16* Vh = Vg + (long)head * HS;  // flash-tile layout

  __shared__ __align__(16) u16 k_s[2][8192];   // 2 x 16 KB  [kt][n][32]
  __shared__ __align__(16) u16 v_s[2][8192];   // 2 x 16 KB  [kt2][d][32]
  __shared__ __align__(16) u16 p_s[4 * 1088];  // 8.5 KB, per-wave 16 x stride-68

  const int tid  = threadIdx.x;
  const int lane = tid & 63, wv = tid >> 6;
  const int lr   = lane & 15, quad = lane >> 4;
  const int qs   = qb * 64 + wv * 16;
  const int pbase = wv * 1088;

  short8 qf[4];
  #pragma unroll
  for (int kt = 0; kt < 4; kt++)
    qf[kt] = *(const short8*)(Qh + (long)(qs + lr) * 128 + kt * 32 + quad * 8);

  float l_r[4];
  #pragma unroll
  for (int r = 0; r < 4; r++) l_r[r] = 0.f;

  floatx4 o[8];
  #pragma unroll
  for (int j = 0; j < 8; j++) o[j] = floatx4{0.f, 0.f, 0.f, 0.f};

  #pragma unroll
  for (int it = 0; it < 4; it++) {
    int Cb = (wv * 4 + it) * 64;
    glds16(Kh + (long)(Cb + lane) * 8, &k_s[0][Cb * 8]);
    glds16(Vh + (long)(Cb + lane) * 8, &v_s[0][Cb * 8]);
  }

  for (int kb = 0; kb < nkt; kb++) {
    const int cur = kb & 1;
    __syncthreads();                     // drains own DMA -> buf[cur] ready
    if (kb + 1 < nkt) {                  // prefetch tile kb+1 into buf[cur^1]
      const u16* Kt = Kh + (long)(kb + 1) * 8192;
      const u16* Vt = Vh + (long)(kb + 1) * 8192;
      #pragma unroll
      for (int it = 0; it < 4; it++) {
        int Cb = (wv * 4 + it) * 64;
        glds16(Kt + (long)(Cb + lane) * 8, &k_s[cur ^ 1][Cb * 8]);
        glds16(Vt + (long)(Cb + lane) * 8, &v_s[cur ^ 1][Cb * 8]);
      }
    }

    floatx4 sa[4];
    #pragma unroll
    for (int j = 0; j < 4; j++) sa[j] = floatx4{0.f, 0.f, 0.f, 0.f};
    #pragma unroll
    for (int kt = 0; kt < 4; kt++) {
      #pragma unroll
      for (int j = 0; j < 4; j++) {
        short8 bf = *(const short8*)(&k_s[cur][kt * 2048 + (j * 16 + lr) * 32 + quad * 8]);
        sa[j] = __builtin_amdgcn_mfma_f32_16x16x32_bf16(qf[kt], bf, sa[j], 0, 0, 0);
      }
    }

    if (kb == nkt - 1) {                 // causal mask, last tile only
      #pragma unroll
      for (int j = 0; j < 4; j++)
        #pragma unroll
        for (int r = 0; r < 4; r++) {
          int cg = kb * 64 + j * 16 + lr;
          int rg = qs + quad * 4 + r;
          if (cg > rg) sa[j][r] = -1e30f;
        }
    }

    #pragma unroll
    for (int r = 0; r < 4; r++) {
      float s0 = 0.f;
      #pragma unroll
      for (int j = 0; j < 4; j++) {
        float e = __expf(sa[j][r] - 8.f);
        p_s[pbase + (quad * 4 + r) * 68 + j * 16 + lr] = f2bf(e);
        s0 += e;
      }
      s0 += __shfl_xor(s0, 1, 16);
      s0 += __shfl_xor(s0, 2, 16);
      s0 += __shfl_xor(s0, 4, 16);
      s0 += __shfl_xor(s0, 8, 16);
      l_r[r] += s0;
    }

    #pragma unroll
    for (int kt2 = 0; kt2 < 2; kt2++) {
      short8 pa = *(const short8*)(&p_s[pbase + lr * 68 + kt2 * 32 + quad * 8]);
      #pragma unroll
      for (int j = 0; j < 8; j++) {
        short8 vb = *(const short8*)(&v_s[cur][kt2 * 4096 + (j * 16 + lr) * 32 + quad * 8]);
        o[j] = __builtin_amdgcn_mfma_f32_16x16x32_bf16(pa, vb, o[j], 0, 0, 0);
      }
    }
  } // kb

  #pragma unroll
  for (int r = 0; r < 4; r++) {
    float inv = 1.f / l_r[r];
    int row = qs + quad * 4 + r;
    long prow = ((long)(row >> 7) * 64) * 4096 + (row & 127) * 32;
    #pragma unroll
    for (int j = 0; j < 8; j++) {
      int c = head * 128 + j * 16 + lr;
      ctx[prow + (long)(c >> 5) * 4096 + (c & 31)] = f2bf(o[j][r] * inv);
    }
  }
}

// fp32 [M][K] row-major -> bf16 swizzled 256-PANELS. float4/thread.
__global__ __launch_bounds__(256)
void convert256_kernel(const float* __restrict__ in, u16* __restrict__ out,
                       int K, long n4)
{
  long i = (long)blockIdx.x * 256 + threadIdx.x;
  if (i < n4) {
    float4 v = ((const float4*)in)[i];
    ushort4 p;
    p.x = f2bf(v.x); p.y = f2bf(v.y); p.z = f2bf(v.z); p.w = f2bf(v.w);
    long e = i * 4;
    int row = (int)(e / K), k = (int)(e % K);
    int nkt = K >> 6;
    long d = ((long)(row >> 8) * nkt + (k >> 6)) * 16384
           + (row & 255) * 64 + ((k & 63) ^ ((row & 7) << 3));
    *(ushort4*)(&out[d]) = p;   // XOR flips bits>=3; 4-run stays contiguous
  }
}

// fp32 [K][N] -> bf16 swizzled 256-PANELS of the [N][K] transpose.
__global__ __launch_bounds__(256)
void transpose256_kernel(const float* __restrict__ in, u16* __restrict__ out,
                         int K, int N)
{
  __shared__ float t[32][33];
  int n0 = blockIdx.x * 32, k0 = blockIdx.y * 32;
  int tx = threadIdx.x & 31, ty = threadIdx.x >> 5;
  #pragma unroll
  for (int i = 0; i < 4; i++)
    t[ty + i * 8][tx] = in[(long)(k0 + ty + i * 8) * N + n0 + tx];
  __syncthreads();
  const int nkt = K >> 6;
  #pragma unroll
  for (int i = 0; i < 4; i++) {
    int n = n0 + ty + i * 8;
    int k = k0 + tx;
    long d = ((long)(n >> 8) * nkt + (k >> 6)) * 16384
           + (n & 255) * 64 + ((k & 63) ^ ((n & 7) << 3));
    out[d] = f2bf(t[tx][ty + i * 8]);
  }
}

// fp32 [K][N] -> bf16 legacy 128-PANELS of the [N][K] transpose. 32x32 tiles.
__global__ __launch_bounds__(256)
void transpose_bf16_kernel(const float* __restrict__ in, u16* __restrict__ out,
                           int K, int N)
{
  __shared__ float t[32][33];
  int n0 = blockIdx.x * 32, k0 = blockIdx.y * 32;
  int tx = threadIdx.x & 31, ty = threadIdx.x >> 5;
  #pragma unroll
  for (int i = 0; i < 4; i++)
    t[ty + i * 8][tx] = in[(long)(k0 + ty + i * 8) * N + n0 + tx];
  __syncthreads();
  const int nkb = K >> 5;
  #pragma unroll
  for (int i = 0; i < 4; i++) {
    int n = n0 + ty + i * 8;
    int k = k0 + tx;
    long d = ((long)(n >> 7) * nkb + (k >> 5)) * 4096 + (n & 127) * 32 + (k & 31);
    out[d] = f2bf(t[tx][ty + i * 8]);
  }
}

// RoPE in-place on first 32 dims of Q (row-major) and K (flash tiles).
__global__ __launch_bounds__(256)
void rope_kernel(u16* __restrict__ Q, u16* __restrict__ K)
{
  int idx = blockIdx.x * 256 + threadIdx.x;
  int i = idx & 15;
  int s = (idx >> 4) & 2047;
  int head = (idx >> 15) & 15;
  int isK = (idx >> 19);
  float inv_freq = exp2f(-(float)i * 0.83048202372184058696f); // 10000^(-i/16)
  float ang = (float)s * inv_freq;
  float c = cosf(ang), sn = sinf(ang);
  long b0, b1;
  u16* buf;
  if (isK) {
    buf = K;
    long base = (long)head * 262144 + (long)(s >> 6) * 8192 + (s & 63) * 32;
    b0 = base + i;
    b1 = base + i + 16;
  } else {
    buf = Q;
    long base = ((long)head * 2048 + s) * 128;
    b0 = base + i;
    b1 = base + i + 16;
  }
  float x1 = bf2f(buf[b0]);
  float x2 = bf2f(buf[b1]);
  buf[b0] = f2bf(x1 * c - x2 * sn);
  buf[b1] = f2bf(x2 * c + x1 * sn);
}

extern "C" void kernel_launch(void* const* d_in, const int* in_sizes, int n_in,
                              void* d_out, int out_size, void* d_ws, size_t ws_size,
                              hipStream_t stream)
{
  const float* hidden = (const float*)d_in[0];   // [2048][2048] f32
  const float* Wqkv   = (const float*)d_in[1];   // [2048][6144] f32
  const float* bqkv   = (const float*)d_in[2];   // [6144] f32
  const float* Wd     = (const float*)d_in[3];   // [2048][2048] f32
  const float* bd     = (const float*)d_in[4];   // [2048] f32
  float* out = (float*)d_out;                    // [2048][2048] f32

  char* ws = (char*)d_ws;
  u16* Q   = (u16*)(ws);                      //  8 MB  Q row-major
  u16* Kb  = (u16*)(ws + (8ull  << 20));      //  8 MB  K flash tiles
  u16* Vt  = (u16*)(ws + (16ull << 20));      //  8 MB  V flash tiles
  u16* ctx = (u16*)(ws + (24ull << 20));      //  8 MB  ctx panels (128-layout)
  char* regA = ws + (32ull << 20);            // overlay region

  const bool fast = ws_size >= (64ull << 20);

  if (fast) {
    u16* hidden_bf = (u16*)(regA);                  // 8 MB 256-panels, then Wd_t
    u16* Wqkv_t    = (u16*)(regA + (8ull << 20));   // 24 MB 256-panels
    u16* Wd_t      = (u16*)(regA);                  // 8 MB 128-panels

    convert256_kernel<<<dim3(4096), 256, 0, stream>>>(hidden, hidden_bf, 2048, 1048576);
    transpose256_kernel<<<dim3(192, 64), 256, 0, stream>>>(Wqkv, Wqkv_t, 2048, 6144);

    gemm8_kernel<<<dim3(24, 8), 512, 0, stream>>>(
        hidden_bf, Wqkv_t, /*NKT*/32, bqkv, Q, Kb, Vt);

    rope_kernel<<<dim3(4096), 256, 0, stream>>>(Q, Kb);
    transpose_bf16_kernel<<<dim3(64, 64), 256, 0, stream>>>(Wd, Wd_t, 2048, 2048);

    flash_kernel<<<dim3(16, 32), 256, 0, stream>>>(Q, Kb, Vt, ctx);

    gemm_dense_kernel<<<dim3(32, 16), 256, 0, stream>>>(
        ctx, Wd_t, /*nkb*/64, bd, out);
  } else {
    gemm_kernel<<<dim3(48, 16, 1), 256, 0, stream>>>(
        hidden, Wqkv, 2048, 2048, 6144, 0, 0, /*mode*/0, 0, 1, 1, bqkv,
        Q, Kb, Vt, nullptr);
    rope_kernel<<<dim3(4096), 256, 0, stream>>>(Q, Kb);
    flash_kernel<<<dim3(16, 32), 256, 0, stream>>>(Q, Kb, Vt, ctx);
    gemm_kernel<<<dim3(16, 16, 1), 256, 0, stream>>>(
        ctx, Wd, 2048, 2048, 2048, 0, 0, /*mode*/3, 0, 0, 1, bd,
        nullptr, nullptr, nullptr, out);
  }
}